// Round 10
// baseline (188.725 us; speedup 1.0000x reference)
//
#include <hip/hip_runtime.h>
#include <math.h>

// Problem dims: B=8, N=512, T=64, D=128, E=32, M=3, BN=4096
// ws layout (float offsets)
#define OFF_QWHI   768        // 6144 floats = 12288 bf16 (qn@spaceW hi)
#define OFF_QWLO   6912       // 6144 floats (lo)
#define OFF_H      13056      // 4096*128
#define OFF_PROBS  537344     // 24
#define OFF_HV     537376     // 4096
#define OFF_SCORES 541472     // 768*512
#define OFF_HMIX   934688     // 8*32*512 = 131072
#define OFF_SHI    1115168    // 24576 floats (spaceW hi)
#define OFF_SLO    1139744    // 24576 floats (spaceW lo)
#define OFF_STATS  1164320    // 256 blocks * 256 floats (per-block slots, no zero)
#define OFF_EV     1229856    // 256 (zeroed by gru extra block)
#define OFF_QB     1230112    // 96 (qn . spaceb)

#define L2E_F 1.44269504088896340736f

typedef short bf16x8 __attribute__((ext_vector_type(8)));
typedef float f32x4 __attribute__((ext_vector_type(4)));

union U8 { unsigned short s[8]; bf16x8 v; uint4 u4; };

__device__ __forceinline__ unsigned short bf16_rtn(float f) {
  unsigned int u = __float_as_uint(f);
  return (unsigned short)((u + 0x7FFFu + ((u >> 16) & 1u)) >> 16);
}
__device__ __forceinline__ float bf16_f(unsigned short h) {
  return __uint_as_float(((unsigned int)h) << 16);
}

// ---------------------------------------------------------------------------
// GRU + fused prep. Grid 280 x 512.
// Blocks 0..255: gru (R6-verified main loop). Prologue computes u/c
//   cooperatively from Wih/projW/projb (stored in hFin LDS area, dead until
//   epilogue) and loads Ah directly from Whh with inline log2e + bf16 RTN
//   (bit-identical to old prep). Stats -> per-block slots (no zeroing).
// Blocks 256..279: prep-extra: SHI/SLO conversion, QW/QB (4 qrows/block),
//   EV zero. Consumed only by later kernels.
// ---------------------------------------------------------------------------
#define GRU_STEP(RB, WB, XSV)                                                       \
  do {                                                                              \
    f32x4 acc0 = c0i, acc1 = c1i, acc2 = c2i;                                       \
    _Pragma("unroll") for (int c = 0; c < 4; ++c) {                                 \
      bf16x8 Bf = *(const bf16x8*)&hB[RB][rdOff + c * 32];                          \
      acc0 = __builtin_amdgcn_mfma_f32_16x16x32_bf16(Bf, Ah[0][c], acc0, 0, 0, 0);  \
      acc1 = __builtin_amdgcn_mfma_f32_16x16x32_bf16(Bf, Ah[1][c], acc1, 0, 0, 0);  \
      acc2 = __builtin_amdgcn_mfma_f32_16x16x32_bf16(Bf, Ah[2][c], acc2, 0, 0, 0);  \
    }                                                                               \
    const float xsv = (XSV);                                                        \
    float hv[4];                                                                    \
    _Pragma("unroll") for (int r = 0; r < 4; ++r) {                                 \
      float gr = fmaf(xsv, ur[r], acc0[r]);                                         \
      float gz = fmaf(xsv, uz[r], acc1[r]);                                         \
      float gn = fmaf(xsv, un[r], cnv[r]);                                          \
      float rr = __builtin_amdgcn_rcpf(1.f + __builtin_amdgcn_exp2f(-gr));          \
      float Ez = __builtin_amdgcn_exp2f(gz);                                        \
      float a = fmaf(rr, acc2[r], gn);                                              \
      float Ea = __builtin_amdgcn_exp2f(a);                                         \
      float u = Ea + 1.f;                                                           \
      float v = Ez + 1.f;                                                           \
      float num = fmaf(1.f - hreg[r], u, -2.f);                                     \
      float hvv = fmaf(num, __builtin_amdgcn_rcpf(u * v), hreg[r]);                 \
      hv[r] = hvv;                                                                  \
      hreg[r] = hvv;                                                                \
    }                                                                               \
    unsigned int pk0, pk1;                                                          \
    asm("v_cvt_pk_bf16_f32 %0, %1, %2" : "=v"(pk0) : "v"(hv[0]), "v"(hv[1]));       \
    asm("v_cvt_pk_bf16_f32 %0, %1, %2" : "=v"(pk1) : "v"(hv[2]), "v"(hv[3]));       \
    *(uint2*)&hB[WB][wrOff] = make_uint2(pk0, pk1);                                 \
    __syncthreads();                                                                \
  } while (0)

__global__ __launch_bounds__(512, 2) void gru_kernel(const float* __restrict__ x,
                                                     const float* __restrict__ bhh,
                                                     const float* __restrict__ outW,
                                                     const float* __restrict__ Wih,
                                                     const float* __restrict__ projW,
                                                     const float* __restrict__ projb,
                                                     const float* __restrict__ bih,
                                                     const float* __restrict__ Whh,
                                                     const float* __restrict__ queries,
                                                     const float* __restrict__ spaceW,
                                                     const float* __restrict__ spaceb,
                                                     float* __restrict__ ws) {
  __shared__ __align__(16) unsigned short hB[2][16 * 136];
  __shared__ __align__(16) float xsAll[16 * 68];
  __shared__ float hFin[16 * 132];   // prologue: uL=hFin[0..383], cL=hFin[512..895]
  __shared__ float qrowL[4][128];    // extra-block path only
  __shared__ float invS4[4], qdS4[4];

  const int tid = threadIdx.x, wave = tid >> 6, lane = tid & 63;

  // ======================= prep-extra blocks =======================
  if (blockIdx.x >= 256) {
    const int bid2 = blockIdx.x - 256;  // 0..23
    // SHI/SLO: spaceW bf16 hi/lo split (2048 elems per block)
    {
      unsigned short* SHI = (unsigned short*)(ws + OFF_SHI);
      unsigned short* SLO = (unsigned short*)(ws + OFF_SLO);
      int base = bid2 * 2048;
#pragma unroll
      for (int p = 0; p < 4; ++p) {
        int i = base + tid + p * 512;
        float w = spaceW[i];
        unsigned short hi = bf16_rtn(w);
        SHI[i] = hi;
        SLO[i] = bf16_rtn(w - bf16_f(hi));
      }
    }
    if (bid2 == 0 && tid < 256) ws[OFF_EV + tid] = 0.f;
    // QW: 4 qrows per block; group g = tid>>7, dtid = tid&127
    const int g = tid >> 7, dtid = tid & 127;
    const int qi = bid2 * 4 + g, m = qi >> 5;
    qrowL[g][dtid] = queries[qi * 128 + dtid];
    __syncthreads();
    {
      int gg = wave >> 1;
      int qig = bid2 * 4 + gg, mg = qig >> 5;
      float v0 = qrowL[gg][lane], v1 = qrowL[gg][64 + lane];
      if ((wave & 1) == 0) {
        float ss = v0 * v0 + v1 * v1;
        for (int off = 32; off; off >>= 1) ss += __shfl_xor(ss, off);
        if (lane == 0) invS4[gg] = 1.f / fmaxf(sqrtf(ss), 1e-12f);
      } else {
        float v = v0 * spaceb[mg * 128 + lane] + v1 * spaceb[mg * 128 + 64 + lane];
        for (int off = 32; off; off >>= 1) v += __shfl_xor(v, off);
        if (lane == 0) qdS4[gg] = v;
      }
    }
    __syncthreads();
    {
      float acc = 0.f;
      const float* sw = spaceW + m * 16384 + dtid;
#pragma unroll 8
      for (int dout = 0; dout < 128; ++dout)
        acc = fmaf(qrowL[g][dout], sw[dout * 128], acc);
      float a = acc * invS4[g];
      unsigned short hi = bf16_rtn(a);
      ((unsigned short*)(ws + OFF_QWHI))[qi * 128 + dtid] = hi;
      ((unsigned short*)(ws + OFF_QWLO))[qi * 128 + dtid] = bf16_rtn(a - bf16_f(hi));
      if (dtid == 0) ws[OFF_QB + qi] = qdS4[g] * invS4[g];
    }
    return;
  }

  // ========================== gru main blocks ==========================
  const int q = lane >> 4, s15 = lane & 15;
  const int d0 = wave * 16 + q * 4;

  // --- prologue A: cooperative u/c (8 waves x 48 rows, coalesced) ---
  {
    float pw0 = projW[lane], pw1 = projW[64 + lane];
    float pb0 = projb[lane], pb1 = projb[64 + lane];
    for (int i = 0; i < 48; ++i) {
      int row = wave * 48 + i;
      float w0 = Wih[row * 128 + lane], w1 = Wih[row * 128 + 64 + lane];
      float uu = w0 * pw0 + w1 * pw1;
      float cc = w0 * pb0 + w1 * pb1;
      for (int off = 32; off; off >>= 1) {
        uu += __shfl_xor(uu, off);
        cc += __shfl_xor(cc, off);
      }
      if (lane == 0) {
        hFin[row] = uu;        // uL
        hFin[512 + row] = cc;  // cL (raw dot; bih added at read)
      }
    }
  }

  // --- prologue B: Ah direct from Whh (inline log2e + bf16 RTN) ---
  bf16x8 Ah[3][4];
#pragma unroll
  for (int t = 0; t < 3; ++t) {
    const float sc = (t == 2) ? (2.f * L2E_F) : L2E_F;
    int row = (wave + 8 * t) * 16 + s15;
#pragma unroll
    for (int c = 0; c < 4; ++c) {
      const float* src = &Whh[row * 128 + c * 32 + q * 8];
      float4 f0 = *(const float4*)src;
      float4 f1 = *(const float4*)(src + 4);
      U8 pk;
      pk.s[0] = bf16_rtn(f0.x * sc); pk.s[1] = bf16_rtn(f0.y * sc);
      pk.s[2] = bf16_rtn(f0.z * sc); pk.s[3] = bf16_rtn(f0.w * sc);
      pk.s[4] = bf16_rtn(f1.x * sc); pk.s[5] = bf16_rtn(f1.y * sc);
      pk.s[6] = bf16_rtn(f1.z * sc); pk.s[7] = bf16_rtn(f1.w * sc);
      Ah[t][c] = pk.v;
    }
  }

  {
    float4 z4 = make_float4(0.f, 0.f, 0.f, 0.f);
    float4* hm4 = (float4*)(ws + OFF_HMIX);
    if (tid < 128) hm4[blockIdx.x * 128 + tid] = z4;
  }

  const int seq0 = blockIdx.x * 16;
  for (int i = tid; i < 1024; i += 512) {
    int s = i >> 6, tt = i & 63;
    int r = (seq0 + s) * 64 + tt;
    xsAll[s * 68 + tt] = x[((r >> 15) * 512 + (r & 511)) * 64 + ((r >> 9) & 63)];
  }
  for (int i = tid; i < 2176; i += 512) hB[0][i] = 0;
  __syncthreads();

  // --- constants from uL/cL + bih/bhh (bit-identical math to prep path) ---
  float ur[4], uz[4], un[4], cnv[4];
  f32x4 c0i, c1i, c2i;
  {
    float4 bi0 = *(const float4*)&bih[d0];
    float4 bi1 = *(const float4*)&bih[128 + d0];
    float4 bi2 = *(const float4*)&bih[256 + d0];
    float4 bh0 = *(const float4*)&bhh[d0];
    float4 bh1 = *(const float4*)&bhh[128 + d0];
    float4 bh2 = *(const float4*)&bhh[256 + d0];
    const float* biP[3] = {(const float*)&bi0, (const float*)&bi1, (const float*)&bi2};
    const float* bhP[3] = {(const float*)&bh0, (const float*)&bh1, (const float*)&bh2};
#pragma unroll
    for (int r = 0; r < 4; ++r) {
      int d = d0 + r;
      ur[r] = hFin[d] * L2E_F;
      uz[r] = hFin[128 + d] * L2E_F;
      un[r] = hFin[256 + d] * (2.f * L2E_F);
      c0i[r] = (hFin[512 + d] + biP[0][r] + bhP[0][r]) * L2E_F;
      c1i[r] = (hFin[512 + 128 + d] + biP[1][r] + bhP[1][r]) * L2E_F;
      cnv[r] = (hFin[512 + 256 + d] + biP[2][r]) * (2.f * L2E_F);
      c2i[r] = bhP[2][r] * (2.f * L2E_F);
    }
  }
  __syncthreads();  // everyone has read uL/cL before hFin is reused in epilogue

  float hreg[4] = {0.f, 0.f, 0.f, 0.f};
  const int rdOff = s15 * 136 + q * 8;
  const int wrOff = s15 * 136 + d0;
  const int xsOff = s15 * 68;

#pragma unroll 1
  for (int t4 = 0; t4 < 16; ++t4) {
    const float4 xs4 = *(const float4*)&xsAll[xsOff + t4 * 4];
    GRU_STEP(0, 1, xs4.x);
    GRU_STEP(1, 0, xs4.y);
    GRU_STEP(0, 1, xs4.z);
    GRU_STEP(1, 0, xs4.w);
  }

#pragma unroll
  for (int r = 0; r < 4; ++r) hFin[s15 * 132 + d0 + r] = hreg[r];
  __syncthreads();
  float* h_out = ws + OFF_H;
#pragma unroll
  for (int p = 0; p < 4; ++p) {
    int item = tid + p * 512;
    int s = item >> 7, dd = item & 127;
    h_out[(seq0 + s) * 128 + dd] = hFin[s * 132 + dd];
  }
  for (int s = wave * 2; s < wave * 2 + 2; ++s) {
    float a = hFin[s * 132 + lane] * outW[lane] + hFin[s * 132 + 64 + lane] * outW[64 + lane];
    for (int off = 32; off; off >>= 1) a += __shfl_xor(a, off);
    if (lane == 0) ws[OFF_HV + seq0 + s] = a;
  }
  if (tid < 128) {
    float s = 0.f, q2 = 0.f;
#pragma unroll
    for (int sI = 0; sI < 16; ++sI) {
      float v = hFin[sI * 132 + tid];
      s += v; q2 += v * v;
    }
    ws[OFF_STATS + blockIdx.x * 256 + tid] = s;
    ws[OFF_STATS + blockIdx.x * 256 + 128 + tid] = q2;
  }
}

// ---------------------------------------------------------------------------
// scores: hs (norm) + score MFMA fused. 384 blocks x 256.
// Blocks with bid%48==0 additionally aggregate per-block stats slots ->
// router -> probs (router dot 3-wave parallel).
// ---------------------------------------------------------------------------
__global__ __launch_bounds__(256) void scores_kernel(const float* __restrict__ spaceb,
                                                     const float* __restrict__ routerW,
                                                     const float* __restrict__ routerb,
                                                     float* __restrict__ ws,
                                                     float* __restrict__ d_out) {
  const int bid = blockIdx.x;
  const int chunk = bid & 15, m = (bid >> 4) % 3, b = bid / 48;
  const int n0 = chunk * 32;
  const int tid = threadIdx.x, wave = tid >> 6, lane = tid & 63;
  const int q = lane >> 4, s15 = lane & 15;

  __shared__ __align__(16) unsigned short sHi[16 * 33 * 8];
  __shared__ __align__(16) unsigned short sLo[16 * 33 * 8];
  __shared__ float hsL[32 * 132];
  __shared__ float biasL[128];
  __shared__ float invnL[32];
  __shared__ float qbL[32];

  const float* hG = ws + OFF_H;
  const unsigned short* SHI = (const unsigned short*)(ws + OFF_SHI);
  const unsigned short* SLO = (const unsigned short*)(ws + OFF_SLO);
  const unsigned short* QWHI = (const unsigned short*)(ws + OFF_QWHI);
  const unsigned short* QWLO = (const unsigned short*)(ws + OFF_QWLO);

  if (tid < 128) biasL[tid] = spaceb[m * 128 + tid];
  else if (tid < 160) qbL[tid - 128] = ws[OFF_QB + m * 32 + (tid - 128)];
  {
    int nn = tid >> 3, kc = tid & 7;
    const float* row = &hG[(b * 512 + n0 + nn) * 128 + kc * 16];
    U8 ph0, pl0, ph1, pl1;
#pragma unroll
    for (int j = 0; j < 8; ++j) {
      float v = row[j];
      unsigned short hi = bf16_rtn(v);
      ph0.s[j] = hi; pl0.s[j] = bf16_rtn(v - bf16_f(hi));
    }
#pragma unroll
    for (int j = 0; j < 8; ++j) {
      float v = row[8 + j];
      unsigned short hi = bf16_rtn(v);
      ph1.s[j] = hi; pl1.s[j] = bf16_rtn(v - bf16_f(hi));
    }
    int g0 = kc * 2;
    *(uint4*)&sHi[(g0 * 33 + nn) * 8] = ph0.u4;
    *(uint4*)&sLo[(g0 * 33 + nn) * 8] = pl0.u4;
    *(uint4*)&sHi[((g0 + 1) * 33 + nn) * 8] = ph1.u4;
    *(uint4*)&sLo[((g0 + 1) * 33 + nn) * 8] = pl1.u4;
  }
  __syncthreads();

  const int nt = wave >> 1;
  const int half = wave & 1;
  const int dt0 = half * 4;
  f32x4 acc[4] = {{0.f,0.f,0.f,0.f},{0.f,0.f,0.f,0.f},{0.f,0.f,0.f,0.f},{0.f,0.f,0.f,0.f}};
  f32x4 accS = {0.f, 0.f, 0.f, 0.f};
#pragma unroll
  for (int c = 0; c < 4; ++c) {
    bf16x8 Ahi = *(const bf16x8*)&sHi[((c * 4 + q) * 33 + nt * 16 + s15) * 8];
    bf16x8 Alo = *(const bf16x8*)&sLo[((c * 4 + q) * 33 + nt * 16 + s15) * 8];
#pragma unroll
    for (int i = 0; i < 4; ++i) {
      int row = m * 16384 + ((dt0 + i) * 16 + s15) * 128 + c * 32 + q * 8;
      bf16x8 Bhi = *(const bf16x8*)&SHI[row];
      bf16x8 Blo = *(const bf16x8*)&SLO[row];
      acc[i] = __builtin_amdgcn_mfma_f32_16x16x32_bf16(Ahi, Bhi, acc[i], 0, 0, 0);
      acc[i] = __builtin_amdgcn_mfma_f32_16x16x32_bf16(Alo, Bhi, acc[i], 0, 0, 0);
      acc[i] = __builtin_amdgcn_mfma_f32_16x16x32_bf16(Ahi, Blo, acc[i], 0, 0, 0);
    }
    {
      int row = (m * 32 + half * 16 + s15) * 128 + c * 32 + q * 8;
      bf16x8 Qhi = *(const bf16x8*)&QWHI[row];
      bf16x8 Qlo = *(const bf16x8*)&QWLO[row];
      accS = __builtin_amdgcn_mfma_f32_16x16x32_bf16(Ahi, Qhi, accS, 0, 0, 0);
      accS = __builtin_amdgcn_mfma_f32_16x16x32_bf16(Alo, Qhi, accS, 0, 0, 0);
      accS = __builtin_amdgcn_mfma_f32_16x16x32_bf16(Ahi, Qlo, accS, 0, 0, 0);
    }
  }
#pragma unroll
  for (int i = 0; i < 4; ++i) {
    int dcol = (dt0 + i) * 16 + s15;
    float bb = biasL[dcol];
#pragma unroll
    for (int r = 0; r < 4; ++r)
      hsL[(nt * 16 + q * 4 + r) * 132 + dcol] = acc[i][r] + bb;
  }
  __syncthreads();

  {
    int n = tid >> 3, kc = tid & 7;
    float ss = 0.f;
#pragma unroll
    for (int d4 = 0; d4 < 4; ++d4) {
      float4 v = *(const float4*)&hsL[n * 132 + kc * 16 + d4 * 4];
      ss += v.x * v.x + v.y * v.y + v.z * v.z + v.w * v.w;
    }
    ss += __shfl_xor(ss, 1); ss += __shfl_xor(ss, 2); ss += __shfl_xor(ss, 4);
    if (kc == 0) invnL[n] = 1.f / fmaxf(sqrtf(ss), 1e-12f);
  }
  __syncthreads();

  {
    int e = half * 16 + s15;
    float qb = qbL[e];
    int nb = nt * 16 + q * 4;
    float4 o;
    o.x = (accS[0] + qb) * invnL[nb + 0];
    o.y = (accS[1] + qb) * invnL[nb + 1];
    o.z = (accS[2] + qb) * invnL[nb + 2];
    o.w = (accS[3] + qb) * invnL[nb + 3];
    *(float4*)&ws[OFF_SCORES + ((b * 3 + m) * 32 + e) * 512 + n0 + nb] = o;
  }

  // probs for this b (only 8 blocks do this)
  if ((bid % 48) == 0) {
    __syncthreads();
    float* st = hsL;
    float* lgS = hsL + 256;
    if (tid < 128) {
      float s = 0.f, q2 = 0.f;
      const float* base = ws + OFF_STATS + b * 32 * 256;
      for (int j = 0; j < 32; ++j) {
        s += base[j * 256 + tid];
        q2 += base[j * 256 + 128 + tid];
      }
      float mean = s * (1.f / 512.f);
      float var = (q2 - 512.f * mean * mean) * (1.f / 511.f);  // ddof=1
      st[tid] = mean;
      st[128 + tid] = sqrtf(fmaxf(var, 0.f));
    }
    __syncthreads();
    if (tid < 192) {
      int w = tid >> 6, ln = tid & 63;
      float acc2 = 0.f;
#pragma unroll
      for (int j = 0; j < 4; ++j)
        acc2 += st[ln * 4 + j] * routerW[w * 256 + ln * 4 + j];
      for (int off = 32; off; off >>= 1) acc2 += __shfl_xor(acc2, off);
      if (ln == 0) lgS[w] = acc2 + routerb[w];
    }
    __syncthreads();
    if (tid == 0) {
      float mx = fmaxf(lgS[0], fmaxf(lgS[1], lgS[2]));
      float e0 = expf(lgS[0] - mx), e1 = expf(lgS[1] - mx), e2 = expf(lgS[2] - mx);
      float inv = 1.f / (e0 + e1 + e2);
      ws[OFF_PROBS + b * 3 + 0] = e0 * inv;
      ws[OFF_PROBS + b * 3 + 1] = e1 * inv;
      ws[OFF_PROBS + b * 3 + 2] = e2 * inv;
      d_out[4096 + b * 3 + 0] = e0 * inv;
      d_out[4096 + b * 3 + 1] = e1 * inv;
      d_out[4096 + b * 3 + 2] = e2 * inv;
    }
  }
}

// ---------------------------------------------------------------------------
// topk: 192 blocks x 256 (4 wave-rows). Scatters Hmix AND accumulates ev.
// ---------------------------------------------------------------------------
__global__ __launch_bounds__(256) void topk_kernel(float* __restrict__ ws) {
  const int row0 = blockIdx.x * 4;
  const int b = row0 / 96;
  const int tid = threadIdx.x, wave = tid >> 6, lane = tid & 63;
  __shared__ float hvL[512];
  hvL[tid] = ws[OFF_HV + b * 512 + tid];
  hvL[256 + tid] = ws[OFF_HV + b * 512 + 256 + tid];
  __syncthreads();

  int row = row0 + wave;
  int m = (row / 32) % 3, e = row & 31;
  const float* sc = ws + OFF_SCORES + row * 512;
  float prob = ws[OFF_PROBS + b * 3 + m];

  float v[8];
#pragma unroll
  for (int j = 0; j < 8; ++j) v[j] = sc[j * 64 + lane];

  float selv = 0.f; int seli = 0; float maxv = 0.f;
  for (int it = 0; it < 25; ++it) {
    float bv = v[0]; int bj = 0;
#pragma unroll
    for (int j = 1; j < 8; ++j)
      if (v[j] > bv) { bv = v[j]; bj = j; }
    int bidx = bj * 64 + lane;
    for (int off = 32; off; off >>= 1) {
      float ov = __shfl_xor(bv, off);
      int oi = __shfl_xor(bidx, off);
      if (ov > bv || (ov == bv && oi < bidx)) { bv = ov; bidx = oi; }
    }
    if (lane == (bidx & 63)) v[bidx >> 6] = -INFINITY;
    if (it == 0) maxv = bv;
    if (lane == it) { selv = bv; seli = bidx; }
  }
  float ex = (lane < 25) ? __expf((selv - maxv) * (1.f / 0.7f)) : 0.f;
  float den = ex;
  for (int off = 32; off; off >>= 1) den += __shfl_xor(den, off);
  float w = prob * ex / den;  // 0 for lanes >= 25
  if (lane < 25)
    atomicAdd(&ws[OFF_HMIX + (b * 32 + e) * 512 + seli], w);
  float evc = (lane < 25) ? w * hvL[seli] : 0.f;
  for (int off = 32; off; off >>= 1) evc += __shfl_xor(evc, off);
  if (lane == 0) atomicAdd(&ws[OFF_EV + b * 32 + e], evc);
}

// ---------------------------------------------------------------------------
// final: 128 blocks (b, 32-n chunk) x 512.
// ---------------------------------------------------------------------------
__global__ __launch_bounds__(512) void final_kernel(const float* __restrict__ prior,
                                                    const float* __restrict__ outb,
                                                    const float* __restrict__ plog,
                                                    float* __restrict__ ws,
                                                    float* __restrict__ d_out) {
  const int bid = blockIdx.x;
  const int b = bid >> 4, ch = bid & 15;
  const int tid = threadIdx.x, wave = tid >> 6, lane = tid & 63;
  __shared__ float hvL[512], evL[32];
  hvL[tid] = ws[OFF_HV + b * 512 + tid];
  if (tid < 32) evL[tid] = ws[OFF_EV + b * 32 + tid];
  __syncthreads();
  float alpha = 1.f / (1.f + expf(-plog[0]));
  float ob = outb[0];
#pragma unroll
  for (int i = 0; i < 4; ++i) {
    int n = ch * 32 + wave * 4 + i;
    const float* pr = prior + n * 512;
    float s1 = 0.f;
#pragma unroll
    for (int j = 0; j < 8; ++j) s1 += pr[j * 64 + lane] * hvL[j * 64 + lane];
    float s2 = 0.f;
    if (lane < 32) s2 = ws[OFF_HMIX + (b * 32 + lane) * 512 + n] * evL[lane];
    float a = alpha * s1 + (1.f - alpha) * s2;
    for (int off = 32; off; off >>= 1) a += __shfl_xor(a, off);
    if (lane == 0) d_out[b * 512 + n] = a + ob;
  }
}

// ---------------------------------------------------------------------------
extern "C" void kernel_launch(void* const* d_in, const int* in_sizes, int n_in,
                              void* d_out, int out_size, void* d_ws, size_t ws_size,
                              hipStream_t stream) {
  const float* x       = (const float*)d_in[0];
  const float* prior   = (const float*)d_in[1];
  const float* projW   = (const float*)d_in[2];
  const float* projb   = (const float*)d_in[3];
  const float* Wih     = (const float*)d_in[4];
  const float* Whh     = (const float*)d_in[5];
  const float* bih     = (const float*)d_in[6];
  const float* bhh     = (const float*)d_in[7];
  const float* spaceW  = (const float*)d_in[8];
  const float* spaceb  = (const float*)d_in[9];
  const float* routerW = (const float*)d_in[10];
  const float* routerb = (const float*)d_in[11];
  const float* outW    = (const float*)d_in[12];
  const float* outb    = (const float*)d_in[13];
  const float* plog    = (const float*)d_in[14];
  const float* queries = (const float*)d_in[15];
  float* ws  = (float*)d_ws;
  float* out = (float*)d_out;

  gru_kernel<<<280, 512, 0, stream>>>(x, bhh, outW, Wih, projW, projb, bih,
                                      Whh, queries, spaceW, spaceb, ws);
  scores_kernel<<<384, 256, 0, stream>>>(spaceb, routerW, routerb, ws, out);
  topk_kernel<<<192, 256, 0, stream>>>(ws);
  final_kernel<<<128, 512, 0, stream>>>(prior, outb, plog, ws, out);
}

// Round 11
// 161.434 us; speedup vs baseline: 1.1691x; 1.1691x over previous
//
#include <hip/hip_runtime.h>
#include <math.h>

// Problem dims: B=8, N=512, T=64, D=128, E=32, M=3, BN=4096
// ws layout (float offsets)
#define OFF_U      0          // 384
#define OFF_C      384        // 384
#define OFF_QWHI   768        // 6144 floats = 12288 bf16 (qn@spaceW hi)
#define OFF_QWLO   6912       // 6144 floats (lo)
#define OFF_H      13056      // 4096*128
#define OFF_PROBS  537344     // 24
#define OFF_HV     537376     // 4096
#define OFF_SCORES 541472     // 768*512
#define OFF_HMIX   934688     // 8*32*512 = 131072
#define OFF_WHI    1066016    // 24576 floats = 49152 bf16 (Whh bf16, log2e-prescaled)
#define OFF_SHI    1115168    // 24576 floats (spaceW hi)
#define OFF_SLO    1139744    // 24576 floats (spaceW lo)
#define OFF_STATS  1164320    // 8 b * 256 floats (atomic sum/sumsq), zeroed by prep
#define OFF_EV     1229856    // 256
#define OFF_QB     1230112    // 96 (qn . spaceb)

#define L2E_F 1.44269504088896340736f

typedef short bf16x8 __attribute__((ext_vector_type(8)));
typedef float f32x4 __attribute__((ext_vector_type(4)));

union U8 { unsigned short s[8]; bf16x8 v; uint4 u4; };

__device__ __forceinline__ unsigned short bf16_rtn(float f) {
  unsigned int u = __float_as_uint(f);
  return (unsigned short)((u + 0x7FFFu + ((u >> 16) & 1u)) >> 16);
}
__device__ __forceinline__ float bf16_f(unsigned short h) {
  return __uint_as_float(((unsigned int)h) << 16);
}

// ---------------------------------------------------------------------------
// prep, all-wide: 225 blocks x 256.
// 0..95:    u/c — one wave per row of Wih
// 96..111:  Whh bf16 (log2e-prescaled: r/z rows *log2e, n rows *2log2e)
// 112..127: spaceW bf16 hi/lo split
// 128..223: QW[m,e,:] = qn[m,e]@spaceW[m] (hi/lo) + qb[m,e]
//           (qrow staged in LDS; dout split across thread halves -> 64-chain)
// 224:      zero ev + zero atomic-stats area
// ---------------------------------------------------------------------------
__global__ __launch_bounds__(256) void prep_kernel(const float* __restrict__ Wih,
                                                   const float* __restrict__ projW,
                                                   const float* __restrict__ projb,
                                                   const float* __restrict__ bih,
                                                   const float* __restrict__ queries,
                                                   const float* __restrict__ Whh,
                                                   const float* __restrict__ spaceW,
                                                   const float* __restrict__ spaceb,
                                                   float* __restrict__ ws) {
  const int bid = blockIdx.x, tid = threadIdx.x;
  const int wave = tid >> 6, lane = tid & 63;
  if (bid < 96) {
    int r = bid * 4 + wave;  // [0,384)
    float w0 = Wih[r * 128 + lane], w1 = Wih[r * 128 + 64 + lane];
    float u = w0 * projW[lane] + w1 * projW[64 + lane];
    float c = w0 * projb[lane] + w1 * projb[64 + lane];
    for (int off = 32; off; off >>= 1) {
      u += __shfl_xor(u, off);
      c += __shfl_xor(c, off);
    }
    if (lane == 0) {
      ws[OFF_U + r] = u;
      ws[OFF_C + r] = c + bih[r];
    }
  } else if (bid < 112) {
    unsigned short* WHI = (unsigned short*)(ws + OFF_WHI);
    int base = (bid - 96) * 3072;
    for (int i = tid; i < 3072; i += 256) {
      int idx = base + i;
      // rows [0,256) = r/z gates: *log2e ; rows [256,384) = n gate: *2*log2e
      float sc = (idx < 32768) ? L2E_F : (2.f * L2E_F);
      WHI[idx] = bf16_rtn(Whh[idx] * sc);
    }
  } else if (bid < 128) {
    unsigned short* SHI = (unsigned short*)(ws + OFF_SHI);
    unsigned short* SLO = (unsigned short*)(ws + OFF_SLO);
    int base = (bid - 112) * 3072;
    for (int i = tid; i < 3072; i += 256) {
      float w = spaceW[base + i];
      unsigned short hi = bf16_rtn(w);
      SHI[base + i] = hi;
      SLO[base + i] = bf16_rtn(w - bf16_f(hi));
    }
  } else if (bid < 224) {
    int qi = bid - 128;  // 0..95
    int m = qi >> 5, e = qi & 31;
    __shared__ float invS, qdS;
    __shared__ float qrowL[128];
    __shared__ float part[128];
    const float* qrow = queries + (m * 32 + e) * 128;
    if (tid < 128) qrowL[tid] = qrow[tid];
    __syncthreads();
    if (wave == 0) {
      float v0 = qrowL[lane], v1 = qrowL[64 + lane];
      float ss = v0 * v0 + v1 * v1;
      for (int off = 32; off; off >>= 1) ss += __shfl_xor(ss, off);
      if (lane == 0) invS = 1.f / fmaxf(sqrtf(ss), 1e-12f);
    } else if (wave == 1) {
      float v = qrowL[lane] * spaceb[m * 128 + lane] +
                qrowL[64 + lane] * spaceb[m * 128 + 64 + lane];
      for (int off = 32; off; off >>= 1) v += __shfl_xor(v, off);
      if (lane == 0) qdS = v;
    }
    // all 256 threads: din = tid&127, dout-half = tid>>7 (64-deep chain)
    {
      int din = tid & 127, h2 = tid >> 7;
      float acc = 0.f;
      const float* sw = spaceW + m * 16384 + (h2 * 64) * 128 + din;
#pragma unroll 8
      for (int dout = 0; dout < 64; ++dout)
        acc = fmaf(qrowL[h2 * 64 + dout], sw[dout * 128], acc);
      if (h2) part[din] = acc;
      __syncthreads();
      if (tid < 128) {
        float a = (acc + part[tid]) * invS;
        unsigned short hi = bf16_rtn(a);
        ((unsigned short*)(ws + OFF_QWHI))[(m * 32 + e) * 128 + tid] = hi;
        ((unsigned short*)(ws + OFF_QWLO))[(m * 32 + e) * 128 + tid] =
            bf16_rtn(a - bf16_f(hi));
      }
      if (tid == 255) ws[OFF_QB + m * 32 + e] = qdS * invS;
    }
  } else {
    ws[OFF_EV + tid] = 0.f;
    for (int i = tid; i < 2048; i += 256) ws[OFF_STATS + i] = 0.f;
  }
}

// ---------------------------------------------------------------------------
// GRU via transposed bf16 MFMA (R6-verified, unchanged): 256 blocks x 512,
// 16 seqs/block, 12 MFMA/wave/step, merged-denominator gates, xs batching,
// atomic stats.
// ---------------------------------------------------------------------------
#define GRU_STEP(RB, WB, XSV)                                                       \
  do {                                                                              \
    f32x4 acc0 = c0i, acc1 = c1i, acc2 = c2i;                                       \
    _Pragma("unroll") for (int c = 0; c < 4; ++c) {                                 \
      bf16x8 Bf = *(const bf16x8*)&hB[RB][rdOff + c * 32];                          \
      acc0 = __builtin_amdgcn_mfma_f32_16x16x32_bf16(Bf, Ah[0][c], acc0, 0, 0, 0);  \
      acc1 = __builtin_amdgcn_mfma_f32_16x16x32_bf16(Bf, Ah[1][c], acc1, 0, 0, 0);  \
      acc2 = __builtin_amdgcn_mfma_f32_16x16x32_bf16(Bf, Ah[2][c], acc2, 0, 0, 0);  \
    }                                                                               \
    const float xsv = (XSV);                                                        \
    float hv[4];                                                                    \
    _Pragma("unroll") for (int r = 0; r < 4; ++r) {                                 \
      float gr = fmaf(xsv, ur[r], acc0[r]);                                         \
      float gz = fmaf(xsv, uz[r], acc1[r]);                                         \
      float gn = fmaf(xsv, un[r], cnv[r]);                                          \
      float rr = __builtin_amdgcn_rcpf(1.f + __builtin_amdgcn_exp2f(-gr));          \
      float Ez = __builtin_amdgcn_exp2f(gz);                                        \
      float a = fmaf(rr, acc2[r], gn);                                              \
      float Ea = __builtin_amdgcn_exp2f(a);                                         \
      float u = Ea + 1.f;                                                           \
      float v = Ez + 1.f;                                                           \
      float num = fmaf(1.f - hreg[r], u, -2.f);                                     \
      float hvv = fmaf(num, __builtin_amdgcn_rcpf(u * v), hreg[r]);                 \
      hv[r] = hvv;                                                                  \
      hreg[r] = hvv;                                                                \
    }                                                                               \
    unsigned int pk0, pk1;                                                          \
    asm("v_cvt_pk_bf16_f32 %0, %1, %2" : "=v"(pk0) : "v"(hv[0]), "v"(hv[1]));       \
    asm("v_cvt_pk_bf16_f32 %0, %1, %2" : "=v"(pk1) : "v"(hv[2]), "v"(hv[3]));       \
    *(uint2*)&hB[WB][wrOff] = make_uint2(pk0, pk1);                                 \
    __syncthreads();                                                                \
  } while (0)

__global__ __launch_bounds__(512, 2) void gru_kernel(const float* __restrict__ x,
                                                     const float* __restrict__ bhh,
                                                     const float* __restrict__ outW,
                                                     float* __restrict__ ws) {
  __shared__ __align__(16) unsigned short hB[2][16 * 136];
  __shared__ __align__(16) float xsAll[16 * 68];
  __shared__ float hFin[16 * 132];

  const int tid = threadIdx.x, wave = tid >> 6, lane = tid & 63;
  const int q = lane >> 4, s15 = lane & 15;
  const int d0 = wave * 16 + q * 4;
  const unsigned short* WHI = (const unsigned short*)(ws + OFF_WHI);

  {
    float4 z4 = make_float4(0.f, 0.f, 0.f, 0.f);
    float4* hm4 = (float4*)(ws + OFF_HMIX);
    if (tid < 128) hm4[blockIdx.x * 128 + tid] = z4;
  }

  bf16x8 Ah[3][4];
#pragma unroll
  for (int t = 0; t < 3; ++t) {
    int row = (wave + 8 * t) * 16 + s15;
#pragma unroll
    for (int c = 0; c < 4; ++c)
      Ah[t][c] = *(const bf16x8*)&WHI[row * 128 + c * 32 + q * 8];
  }

  float ur[4], uz[4], un[4], cnv[4];
  f32x4 c0i, c1i, c2i;
#pragma unroll
  for (int r = 0; r < 4; ++r) {
    int d = d0 + r;
    ur[r] = ws[OFF_U + d] * L2E_F;
    uz[r] = ws[OFF_U + 128 + d] * L2E_F;
    un[r] = ws[OFF_U + 256 + d] * (2.f * L2E_F);
    c0i[r] = (ws[OFF_C + d] + bhh[d]) * L2E_F;
    c1i[r] = (ws[OFF_C + 128 + d] + bhh[128 + d]) * L2E_F;
    cnv[r] = ws[OFF_C + 256 + d] * (2.f * L2E_F);
    c2i[r] = bhh[256 + d] * (2.f * L2E_F);
  }

  const int seq0 = blockIdx.x * 16;
  for (int i = tid; i < 1024; i += 512) {
    int s = i >> 6, tt = i & 63;
    int r = (seq0 + s) * 64 + tt;
    xsAll[s * 68 + tt] = x[((r >> 15) * 512 + (r & 511)) * 64 + ((r >> 9) & 63)];
  }
  for (int i = tid; i < 2176; i += 512) hB[0][i] = 0;
  __syncthreads();

  float hreg[4] = {0.f, 0.f, 0.f, 0.f};
  const int rdOff = s15 * 136 + q * 8;
  const int wrOff = s15 * 136 + d0;
  const int xsOff = s15 * 68;

#pragma unroll 1
  for (int t4 = 0; t4 < 16; ++t4) {
    const float4 xs4 = *(const float4*)&xsAll[xsOff + t4 * 4];
    GRU_STEP(0, 1, xs4.x);
    GRU_STEP(1, 0, xs4.y);
    GRU_STEP(0, 1, xs4.z);
    GRU_STEP(1, 0, xs4.w);
  }

#pragma unroll
  for (int r = 0; r < 4; ++r) hFin[s15 * 132 + d0 + r] = hreg[r];
  __syncthreads();
  float* h_out = ws + OFF_H;
#pragma unroll
  for (int p = 0; p < 4; ++p) {
    int item = tid + p * 512;
    int s = item >> 7, dd = item & 127;
    h_out[(seq0 + s) * 128 + dd] = hFin[s * 132 + dd];
  }
  for (int s = wave * 2; s < wave * 2 + 2; ++s) {
    float a = hFin[s * 132 + lane] * outW[lane] + hFin[s * 132 + 64 + lane] * outW[64 + lane];
    for (int off = 32; off; off >>= 1) a += __shfl_xor(a, off);
    if (lane == 0) ws[OFF_HV + seq0 + s] = a;
  }
  if (tid < 128) {
    float s = 0.f, q2 = 0.f;
#pragma unroll
    for (int sI = 0; sI < 16; ++sI) {
      float v = hFin[sI * 132 + tid];
      s += v; q2 += v * v;
    }
    int b = blockIdx.x >> 5;
    atomicAdd(&ws[OFF_STATS + b * 256 + tid], s);
    atomicAdd(&ws[OFF_STATS + b * 256 + 128 + tid], q2);
  }
}

// ---------------------------------------------------------------------------
// scores: hs (norm) + score MFMA fused. 384 blocks x 256.
// Blocks with bid%48==0 additionally compute stats->router->probs for b
// (stats read directly from the atomic area; router dot 3-wave parallel).
// ---------------------------------------------------------------------------
__global__ __launch_bounds__(256) void scores_kernel(const float* __restrict__ spaceb,
                                                     const float* __restrict__ routerW,
                                                     const float* __restrict__ routerb,
                                                     float* __restrict__ ws,
                                                     float* __restrict__ d_out) {
  const int bid = blockIdx.x;
  const int chunk = bid & 15, m = (bid >> 4) % 3, b = bid / 48;
  const int n0 = chunk * 32;
  const int tid = threadIdx.x, wave = tid >> 6, lane = tid & 63;
  const int q = lane >> 4, s15 = lane & 15;

  __shared__ __align__(16) unsigned short sHi[16 * 33 * 8];
  __shared__ __align__(16) unsigned short sLo[16 * 33 * 8];
  __shared__ float hsL[32 * 132];
  __shared__ float biasL[128];
  __shared__ float invnL[32];
  __shared__ float qbL[32];

  const float* hG = ws + OFF_H;
  const unsigned short* SHI = (const unsigned short*)(ws + OFF_SHI);
  const unsigned short* SLO = (const unsigned short*)(ws + OFF_SLO);
  const unsigned short* QWHI = (const unsigned short*)(ws + OFF_QWHI);
  const unsigned short* QWLO = (const unsigned short*)(ws + OFF_QWLO);

  if (tid < 128) biasL[tid] = spaceb[m * 128 + tid];
  else if (tid < 160) qbL[tid - 128] = ws[OFF_QB + m * 32 + (tid - 128)];
  {
    int nn = tid >> 3, kc = tid & 7;
    const float* row = &hG[(b * 512 + n0 + nn) * 128 + kc * 16];
    U8 ph0, pl0, ph1, pl1;
#pragma unroll
    for (int j = 0; j < 8; ++j) {
      float v = row[j];
      unsigned short hi = bf16_rtn(v);
      ph0.s[j] = hi; pl0.s[j] = bf16_rtn(v - bf16_f(hi));
    }
#pragma unroll
    for (int j = 0; j < 8; ++j) {
      float v = row[8 + j];
      unsigned short hi = bf16_rtn(v);
      ph1.s[j] = hi; pl1.s[j] = bf16_rtn(v - bf16_f(hi));
    }
    int g0 = kc * 2;
    *(uint4*)&sHi[(g0 * 33 + nn) * 8] = ph0.u4;
    *(uint4*)&sLo[(g0 * 33 + nn) * 8] = pl0.u4;
    *(uint4*)&sHi[((g0 + 1) * 33 + nn) * 8] = ph1.u4;
    *(uint4*)&sLo[((g0 + 1) * 33 + nn) * 8] = pl1.u4;
  }
  __syncthreads();

  const int nt = wave >> 1;
  const int half = wave & 1;
  const int dt0 = half * 4;
  f32x4 acc[4] = {{0.f,0.f,0.f,0.f},{0.f,0.f,0.f,0.f},{0.f,0.f,0.f,0.f},{0.f,0.f,0.f,0.f}};
  f32x4 accS = {0.f, 0.f, 0.f, 0.f};
#pragma unroll
  for (int c = 0; c < 4; ++c) {
    bf16x8 Ahi = *(const bf16x8*)&sHi[((c * 4 + q) * 33 + nt * 16 + s15) * 8];
    bf16x8 Alo = *(const bf16x8*)&sLo[((c * 4 + q) * 33 + nt * 16 + s15) * 8];
#pragma unroll
    for (int i = 0; i < 4; ++i) {
      int row = m * 16384 + ((dt0 + i) * 16 + s15) * 128 + c * 32 + q * 8;
      bf16x8 Bhi = *(const bf16x8*)&SHI[row];
      bf16x8 Blo = *(const bf16x8*)&SLO[row];
      acc[i] = __builtin_amdgcn_mfma_f32_16x16x32_bf16(Ahi, Bhi, acc[i], 0, 0, 0);
      acc[i] = __builtin_amdgcn_mfma_f32_16x16x32_bf16(Alo, Bhi, acc[i], 0, 0, 0);
      acc[i] = __builtin_amdgcn_mfma_f32_16x16x32_bf16(Ahi, Blo, acc[i], 0, 0, 0);
    }
    {
      int row = (m * 32 + half * 16 + s15) * 128 + c * 32 + q * 8;
      bf16x8 Qhi = *(const bf16x8*)&QWHI[row];
      bf16x8 Qlo = *(const bf16x8*)&QWLO[row];
      accS = __builtin_amdgcn_mfma_f32_16x16x32_bf16(Ahi, Qhi, accS, 0, 0, 0);
      accS = __builtin_amdgcn_mfma_f32_16x16x32_bf16(Alo, Qhi, accS, 0, 0, 0);
      accS = __builtin_amdgcn_mfma_f32_16x16x32_bf16(Ahi, Qlo, accS, 0, 0, 0);
    }
  }
#pragma unroll
  for (int i = 0; i < 4; ++i) {
    int dcol = (dt0 + i) * 16 + s15;
    float bb = biasL[dcol];
#pragma unroll
    for (int r = 0; r < 4; ++r)
      hsL[(nt * 16 + q * 4 + r) * 132 + dcol] = acc[i][r] + bb;
  }
  __syncthreads();

  {
    int n = tid >> 3, kc = tid & 7;
    float ss = 0.f;
#pragma unroll
    for (int d4 = 0; d4 < 4; ++d4) {
      float4 v = *(const float4*)&hsL[n * 132 + kc * 16 + d4 * 4];
      ss += v.x * v.x + v.y * v.y + v.z * v.z + v.w * v.w;
    }
    ss += __shfl_xor(ss, 1); ss += __shfl_xor(ss, 2); ss += __shfl_xor(ss, 4);
    if (kc == 0) invnL[n] = 1.f / fmaxf(sqrtf(ss), 1e-12f);
  }
  __syncthreads();

  {
    int e = half * 16 + s15;
    float qb = qbL[e];
    int nb = nt * 16 + q * 4;
    float4 o;
    o.x = (accS[0] + qb) * invnL[nb + 0];
    o.y = (accS[1] + qb) * invnL[nb + 1];
    o.z = (accS[2] + qb) * invnL[nb + 2];
    o.w = (accS[3] + qb) * invnL[nb + 3];
    *(float4*)&ws[OFF_SCORES + ((b * 3 + m) * 32 + e) * 512 + n0 + nb] = o;
  }

  // probs for this b (only 8 blocks do this)
  if ((bid % 48) == 0) {
    __syncthreads();
    float* st = hsL;
    float* lgS = hsL + 256;
    if (tid < 128) {
      float s = ws[OFF_STATS + b * 256 + tid];
      float q2 = ws[OFF_STATS + b * 256 + 128 + tid];
      float mean = s * (1.f / 512.f);
      float var = (q2 - 512.f * mean * mean) * (1.f / 511.f);  // ddof=1
      st[tid] = mean;
      st[128 + tid] = sqrtf(fmaxf(var, 0.f));
    }
    __syncthreads();
    if (tid < 192) {
      int w = tid >> 6, ln = tid & 63;
      float acc2 = 0.f;
#pragma unroll
      for (int j = 0; j < 4; ++j)
        acc2 += st[ln * 4 + j] * routerW[w * 256 + ln * 4 + j];
      for (int off = 32; off; off >>= 1) acc2 += __shfl_xor(acc2, off);
      if (ln == 0) lgS[w] = acc2 + routerb[w];
    }
    __syncthreads();
    if (tid == 0) {
      float mx = fmaxf(lgS[0], fmaxf(lgS[1], lgS[2]));
      float e0 = expf(lgS[0] - mx), e1 = expf(lgS[1] - mx), e2 = expf(lgS[2] - mx);
      float inv = 1.f / (e0 + e1 + e2);
      ws[OFF_PROBS + b * 3 + 0] = e0 * inv;
      ws[OFF_PROBS + b * 3 + 1] = e1 * inv;
      ws[OFF_PROBS + b * 3 + 2] = e2 * inv;
      d_out[4096 + b * 3 + 0] = e0 * inv;
      d_out[4096 + b * 3 + 1] = e1 * inv;
      d_out[4096 + b * 3 + 2] = e2 * inv;
    }
  }
}

// ---------------------------------------------------------------------------
// topk: 192 blocks x 256 (4 wave-rows). Scatters Hmix AND accumulates ev.
// ---------------------------------------------------------------------------
__global__ __launch_bounds__(256) void topk_kernel(float* __restrict__ ws) {
  const int row0 = blockIdx.x * 4;
  const int b = row0 / 96;
  const int tid = threadIdx.x, wave = tid >> 6, lane = tid & 63;
  __shared__ float hvL[512];
  hvL[tid] = ws[OFF_HV + b * 512 + tid];
  hvL[256 + tid] = ws[OFF_HV + b * 512 + 256 + tid];
  __syncthreads();

  int row = row0 + wave;
  int m = (row / 32) % 3, e = row & 31;
  const float* sc = ws + OFF_SCORES + row * 512;
  float prob = ws[OFF_PROBS + b * 3 + m];

  float v[8];
#pragma unroll
  for (int j = 0; j < 8; ++j) v[j] = sc[j * 64 + lane];

  float selv = 0.f; int seli = 0; float maxv = 0.f;
  for (int it = 0; it < 25; ++it) {
    float bv = v[0]; int bj = 0;
#pragma unroll
    for (int j = 1; j < 8; ++j)
      if (v[j] > bv) { bv = v[j]; bj = j; }
    int bidx = bj * 64 + lane;
    for (int off = 32; off; off >>= 1) {
      float ov = __shfl_xor(bv, off);
      int oi = __shfl_xor(bidx, off);
      if (ov > bv || (ov == bv && oi < bidx)) { bv = ov; bidx = oi; }
    }
    if (lane == (bidx & 63)) v[bidx >> 6] = -INFINITY;
    if (it == 0) maxv = bv;
    if (lane == it) { selv = bv; seli = bidx; }
  }
  float ex = (lane < 25) ? __expf((selv - maxv) * (1.f / 0.7f)) : 0.f;
  float den = ex;
  for (int off = 32; off; off >>= 1) den += __shfl_xor(den, off);
  float w = prob * ex / den;  // 0 for lanes >= 25
  if (lane < 25)
    atomicAdd(&ws[OFF_HMIX + (b * 32 + e) * 512 + seli], w);
  float evc = (lane < 25) ? w * hvL[seli] : 0.f;
  for (int off = 32; off; off >>= 1) evc += __shfl_xor(evc, off);
  if (lane == 0) atomicAdd(&ws[OFF_EV + b * 32 + e], evc);
}

// ---------------------------------------------------------------------------
// final: 128 blocks (b, 32-n chunk) x 512.
// ---------------------------------------------------------------------------
__global__ __launch_bounds__(512) void final_kernel(const float* __restrict__ prior,
                                                    const float* __restrict__ outb,
                                                    const float* __restrict__ plog,
                                                    float* __restrict__ ws,
                                                    float* __restrict__ d_out) {
  const int bid = blockIdx.x;
  const int b = bid >> 4, ch = bid & 15;
  const int tid = threadIdx.x, wave = tid >> 6, lane = tid & 63;
  __shared__ float hvL[512], evL[32];
  hvL[tid] = ws[OFF_HV + b * 512 + tid];
  if (tid < 32) evL[tid] = ws[OFF_EV + b * 32 + tid];
  __syncthreads();
  float alpha = 1.f / (1.f + expf(-plog[0]));
  float ob = outb[0];
#pragma unroll
  for (int i = 0; i < 4; ++i) {
    int n = ch * 32 + wave * 4 + i;
    const float* pr = prior + n * 512;
    float s1 = 0.f;
#pragma unroll
    for (int j = 0; j < 8; ++j) s1 += pr[j * 64 + lane] * hvL[j * 64 + lane];
    float s2 = 0.f;
    if (lane < 32) s2 = ws[OFF_HMIX + (b * 32 + lane) * 512 + n] * evL[lane];
    float a = alpha * s1 + (1.f - alpha) * s2;
    for (int off = 32; off; off >>= 1) a += __shfl_xor(a, off);
    if (lane == 0) d_out[b * 512 + n] = a + ob;
  }
}

// ---------------------------------------------------------------------------
extern "C" void kernel_launch(void* const* d_in, const int* in_sizes, int n_in,
                              void* d_out, int out_size, void* d_ws, size_t ws_size,
                              hipStream_t stream) {
  const float* x       = (const float*)d_in[0];
  const float* prior   = (const float*)d_in[1];
  const float* projW   = (const float*)d_in[2];
  const float* projb   = (const float*)d_in[3];
  const float* Wih     = (const float*)d_in[4];
  const float* Whh     = (const float*)d_in[5];
  const float* bih     = (const float*)d_in[6];
  const float* bhh     = (const float*)d_in[7];
  const float* spaceW  = (const float*)d_in[8];
  const float* spaceb  = (const float*)d_in[9];
  const float* routerW = (const float*)d_in[10];
  const float* routerb = (const float*)d_in[11];
  const float* outW    = (const float*)d_in[12];
  const float* outb    = (const float*)d_in[13];
  const float* plog    = (const float*)d_in[14];
  const float* queries = (const float*)d_in[15];
  float* ws  = (float*)d_ws;
  float* out = (float*)d_out;

  prep_kernel<<<225, 256, 0, stream>>>(Wih, projW, projb, bih, queries, Whh,
                                       spaceW, spaceb, ws);
  gru_kernel<<<256, 512, 0, stream>>>(x, bhh, outW, ws);
  scores_kernel<<<384, 256, 0, stream>>>(spaceb, routerW, routerb, ws, out);
  topk_kernel<<<192, 256, 0, stream>>>(ws);
  final_kernel<<<128, 512, 0, stream>>>(prior, outb, plog, ws, out);
}